// Round 2
// baseline (2604.518 us; speedup 1.0000x reference)
//
#include <hip/hip_runtime.h>
#include <math.h>

// ---------------------------------------------------------------------------
// B=2048, N=15, C=1024, H=16, HS=64; M = B*N = 30720 rows.
// All GEMMs: A[M][K] bf16 x Bt[N][K] bf16 (weights pre-transposed) -> C.
// MFMA 16x16x32 bf16 verified layouts:
//   A frag : lane holds A[m=lane&15][k=(lane>>4)*8+j], j=0..7
//   B frag : lane holds B[k=(lane>>4)*8+j][n=lane&15]  (== Bt[n][k] rows)
//   D      : lane reg r holds D[row=(lane>>4)*4+r][col=lane&15]
//
// ws-ADAPTIVE: qkv (377MB for full batch) processed in CH chunks of
// 30720/CH rows (CH in {1,2,4,8,16}; chunk = multiple of 1920 = lcm(128,15)).
// peak ws = 205,520,896 + 754,974,720/CH bytes  (CH=16 -> 241 MiB).
// ---------------------------------------------------------------------------

typedef __attribute__((ext_vector_type(8))) short short8;
typedef __attribute__((ext_vector_type(4))) float fx4;

#define MROWS 30720

__device__ inline unsigned short f2bf(float f) {
    unsigned int u = __float_as_uint(f);
    unsigned int r = (u + 0x7fffu + ((u >> 16) & 1u)) >> 16;
    return (unsigned short)r;
}
__device__ inline float bf2f(unsigned short s) {
    return __uint_as_float(((unsigned int)s) << 16);
}

// ---------------- weight transpose + bf16 cast:  W[K][N] -> Wt[N][K] --------
__global__ __launch_bounds__(256) void transpose_w(const float* __restrict__ W,
                                                   unsigned short* __restrict__ Wt,
                                                   int K, int N) {
    __shared__ float tile[32][33];
    int bn = blockIdx.x * 32;
    int bk = blockIdx.y * 32;
    int tx = threadIdx.x & 31, ty = threadIdx.x >> 5;   // 32 x 8
    #pragma unroll
    for (int i = ty; i < 32; i += 8)
        tile[i][tx] = W[(size_t)(bk + i) * N + bn + tx];
    __syncthreads();
    #pragma unroll
    for (int i = ty; i < 32; i += 8)
        Wt[(size_t)(bn + i) * K + bk + tx] = f2bf(tile[tx][i]);
}

// ---------------- LayerNorm over C=1024, fp32 in -> bf16 out ---------------
// gridDim.y==2 selects stream (a/b); used with y==1 grid for single stream.
__global__ __launch_bounds__(256) void ln_dual(const float* __restrict__ xa,
                                               const float* __restrict__ ga,
                                               const float* __restrict__ bba,
                                               unsigned short* __restrict__ oa,
                                               const float* __restrict__ xb,
                                               const float* __restrict__ gb,
                                               const float* __restrict__ bbb,
                                               unsigned short* __restrict__ ob) {
    const float* x = blockIdx.y ? xb : xa;
    const float* g = blockIdx.y ? gb : ga;
    const float* bv = blockIdx.y ? bbb : bba;
    unsigned short* out = blockIdx.y ? ob : oa;

    int row = blockIdx.x;
    int t = threadIdx.x;
    const float4* xp = (const float4*)(x + (size_t)row * 1024);
    float4 v = xp[t];
    float s  = v.x + v.y + v.z + v.w;
    float ss = v.x * v.x + v.y * v.y + v.z * v.z + v.w * v.w;
    #pragma unroll
    for (int o = 32; o > 0; o >>= 1) { s += __shfl_down(s, o); ss += __shfl_down(ss, o); }
    __shared__ float ps[4], pss[4], stat[2];
    int wv = t >> 6, ln = t & 63;
    if (ln == 0) { ps[wv] = s; pss[wv] = ss; }
    __syncthreads();
    if (t == 0) {
        float S = ps[0] + ps[1] + ps[2] + ps[3];
        float SS = pss[0] + pss[1] + pss[2] + pss[3];
        float m = S * (1.0f / 1024.0f);
        float var = SS * (1.0f / 1024.0f) - m * m;
        stat[0] = m; stat[1] = rsqrtf(var + 1e-5f);
    }
    __syncthreads();
    float m = stat[0], r = stat[1];
    float4 gg = ((const float4*)g)[t];
    float4 bb = ((const float4*)bv)[t];
    ushort4 o;
    o.x = f2bf((v.x - m) * r * gg.x + bb.x);
    o.y = f2bf((v.y - m) * r * gg.y + bb.y);
    o.z = f2bf((v.z - m) * r * gg.z + bb.z);
    o.w = f2bf((v.w - m) * r * gg.w + bb.w);
    ((ushort4*)(out + (size_t)row * 1024))[t] = o;
}

// ---------------- bf16 MFMA GEMM, Bt input, fused epilogues ----------------
// EPI 0: outB = bf16(acc); gridDim.z==2 selects (A,Bt,outB) vs (A2,Bt2,outB2)
// EPI 1: outF = acc + bias[col] + resid[row][col]        (fp32 out)
// EPI 2: outB = bf16(gelu_exact(acc + bias[col]))
template <int EPI, int K>
__global__ __launch_bounds__(256) void gemm_bt(const unsigned short* __restrict__ A,
                                               const unsigned short* __restrict__ Bt,
                                               const unsigned short* __restrict__ A2,
                                               const unsigned short* __restrict__ Bt2,
                                               const float* __restrict__ bias,
                                               const float* __restrict__ resid,
                                               float* __restrict__ outF,
                                               unsigned short* __restrict__ outB,
                                               unsigned short* __restrict__ outB2,
                                               int N) {
    if (EPI == 0 && blockIdx.z) { A = A2; Bt = Bt2; outB = outB2; }
    int wave = threadIdx.x >> 6;
    int lane = threadIdx.x & 63;
    int rowf = lane & 15, quad = lane >> 4;
    int m0 = blockIdx.y * 128 + (wave >> 1) * 64;
    int n0 = blockIdx.x * 128 + (wave & 1) * 64;

    fx4 acc[4][4] = {};
    const short* Ap = (const short*)A;
    const short* Bp = (const short*)Bt;

    for (int k0 = 0; k0 < K; k0 += 32) {
        int ka = k0 + quad * 8;
        short8 a[4], b[4];
        #pragma unroll
        for (int i = 0; i < 4; i++)
            a[i] = *(const short8*)(Ap + (size_t)(m0 + 16 * i + rowf) * K + ka);
        #pragma unroll
        for (int j = 0; j < 4; j++)
            b[j] = *(const short8*)(Bp + (size_t)(n0 + 16 * j + rowf) * K + ka);
        #pragma unroll
        for (int i = 0; i < 4; i++)
            #pragma unroll
            for (int j = 0; j < 4; j++)
                acc[i][j] = __builtin_amdgcn_mfma_f32_16x16x32_bf16(a[i], b[j], acc[i][j], 0, 0, 0);
    }

    #pragma unroll
    for (int i = 0; i < 4; i++) {
        #pragma unroll
        for (int j = 0; j < 4; j++) {
            int col = n0 + 16 * j + rowf;
            #pragma unroll
            for (int r = 0; r < 4; r++) {
                int row = m0 + 16 * i + quad * 4 + r;
                size_t off = (size_t)row * N + col;
                float v = acc[i][j][r];
                if (EPI == 0) {
                    outB[off] = f2bf(v);
                } else if (EPI == 1) {
                    outF[off] = v + bias[col] + resid[off];
                } else {
                    v += bias[col];
                    v = 0.5f * v * (1.0f + erff(v * 0.70710678118654752f));
                    outB[off] = f2bf(v);
                }
            }
        }
    }
}

// ---------------- attention: one block per (chunk-local b, h) --------------
// logits = (Jq.Jk^T + Iq.Ik^T + Iv@Wc) * 0.125 ; softmax ; out = P @ Jv
__global__ __launch_bounds__(256) void attn_kernel(const unsigned short* __restrict__ Jqkv,
                                                   const unsigned short* __restrict__ Iqkv,
                                                   const float* __restrict__ Wc,
                                                   unsigned short* __restrict__ xout) {
    int b = blockIdx.x >> 4;
    int h = blockIdx.x & 15;
    __shared__ float J[3][15][65];
    __shared__ float I[3][15][65];
    __shared__ float W[64][17];
    __shared__ float P[15][16];

    const unsigned short* Jb = Jqkv + (size_t)b * 15 * 3072 + h * 64;
    const unsigned short* Ib = Iqkv + (size_t)b * 15 * 3072 + h * 64;

    for (int idx = threadIdx.x; idx < 15 * 3 * 64; idx += 256) {
        int n = idx / 192, rem = idx % 192;
        int r = rem / 64, d = rem % 64;
        J[r][n][d] = bf2f(Jb[(size_t)n * 3072 + r * 1024 + d]);
        I[r][n][d] = bf2f(Ib[(size_t)n * 3072 + r * 1024 + d]);
    }
    for (int idx = threadIdx.x; idx < 64 * 15; idx += 256)
        W[idx / 15][idx % 15] = Wc[idx];
    __syncthreads();

    for (int idx = threadIdx.x; idx < 225; idx += 256) {
        int q = idx / 15, kk = idx % 15;
        float s = 0.0f;
        #pragma unroll 8
        for (int d = 0; d < 64; d++)
            s += J[0][q][d] * J[1][kk][d] + I[0][q][d] * I[1][kk][d] + I[2][q][d] * W[d][kk];
        P[q][kk] = s * 0.125f;
    }
    __syncthreads();

    if (threadIdx.x < 15) {
        int q = threadIdx.x;
        float mx = -1e30f;
        #pragma unroll
        for (int kk = 0; kk < 15; kk++) mx = fmaxf(mx, P[q][kk]);
        float e[15], sum = 0.0f;
        #pragma unroll
        for (int kk = 0; kk < 15; kk++) { e[kk] = __expf(P[q][kk] - mx); sum += e[kk]; }
        float inv = 1.0f / sum;
        #pragma unroll
        for (int kk = 0; kk < 15; kk++) P[q][kk] = e[kk] * inv;
    }
    __syncthreads();

    for (int idx = threadIdx.x; idx < 960; idx += 256) {
        int q = idx >> 6, d = idx & 63;
        float o = 0.0f;
        #pragma unroll
        for (int kk = 0; kk < 15; kk++) o += P[q][kk] * J[2][kk][d];
        xout[((size_t)b * 15 + q) * 1024 + h * 64 + d] = f2bf(o);
    }
}

// ---------------------------------------------------------------------------
extern "C" void kernel_launch(void* const* d_in, const int* in_sizes, int n_in,
                              void* d_out, int out_size, void* d_ws, size_t ws_size,
                              hipStream_t stream) {
    const float* joint_feature    = (const float*)d_in[0];
    const float* relation_feature = (const float*)d_in[1];
    const float* W_Jqkv  = (const float*)d_in[2];
    const float* W_Iqk   = (const float*)d_in[3];
    const float* W_Iconv = (const float*)d_in[4];
    const float* W_proj  = (const float*)d_in[5];
    const float* b_proj  = (const float*)d_in[6];
    const float* g1  = (const float*)d_in[7];
    const float* be1 = (const float*)d_in[8];
    const float* g2  = (const float*)d_in[9];
    const float* be2 = (const float*)d_in[10];
    const float* gj  = (const float*)d_in[11];
    const float* bj  = (const float*)d_in[12];
    const float* W_fc1 = (const float*)d_in[13];
    const float* b_fc1 = (const float*)d_in[14];
    const float* W_fc2 = (const float*)d_in[15];
    const float* b_fc2 = (const float*)d_in[16];

    char* ws = (char*)d_ws;
    // -------- fixed region [0, 205,520,896) --------
    unsigned short* WtJ  = (unsigned short*)(ws + 0);          //  6,291,456  [3072][1024]
    unsigned short* WtI  = (unsigned short*)(ws + 6291456);    //  6,291,456  [3072][1024]
    unsigned short* WtP  = (unsigned short*)(ws + 12582912);   //  2,097,152  [1024][1024]
    unsigned short* WtF1 = (unsigned short*)(ws + 14680064);   //  1,048,576  [512][1024]
    unsigned short* WtF2 = (unsigned short*)(ws + 15728640);   //  1,048,576  [1024][512]
    unsigned short* xj   = (unsigned short*)(ws + 16777216);   // 62,914,560  [M][1024] bf16
    unsigned short* xi   = (unsigned short*)(ws + 79691776);   // 62,914,560  [M][1024] bf16
    unsigned short* xattn = (unsigned short*)(ws + 142606336); // 62,914,560  [M][1024] bf16
    // -------- reused regions --------
    float*          joint = (float*)(ws + 16777216);           // fp32 [M][1024] over dead xj+xi
    unsigned short* yln   = xattn;                             // bf16, xattn dead after proj
    unsigned short* h1    = (unsigned short*)(ws + 205520896); // bf16 [M][512], chunk bufs dead
    // -------- chunked qkv region @205,520,896 --------
    // pick smallest CH whose peak fits ws_size; CH=16 fallback (241 MiB peak)
    int CH = 16;
    {
        const int opts[5] = {1, 2, 4, 8, 16};
        for (int i = 0; i < 5; i++) {
            size_t need = 205520896ull + 754974720ull / (size_t)opts[i];
            if (need <= ws_size) { CH = opts[i]; break; }
        }
    }
    const int Mc = MROWS / CH;                      // rows per chunk (multiple of 1920)
    const size_t chunkBytes = 754974720ull / (size_t)CH / 2ull;  // per qkv buffer
    unsigned short* Jqkv_c = (unsigned short*)(ws + 205520896);
    unsigned short* Iqkv_c = (unsigned short*)(ws + 205520896 + chunkBytes);

    dim3 blk(256);

    // 1) transpose + bf16-cast weights
    transpose_w<<<dim3(96, 32), blk, 0, stream>>>(W_Jqkv, WtJ, 1024, 3072);
    transpose_w<<<dim3(96, 32), blk, 0, stream>>>(W_Iqk,  WtI, 1024, 3072);
    transpose_w<<<dim3(32, 32), blk, 0, stream>>>(W_proj, WtP, 1024, 1024);
    transpose_w<<<dim3(16, 32), blk, 0, stream>>>(W_fc1, WtF1, 1024, 512);
    transpose_w<<<dim3(32, 16), blk, 0, stream>>>(W_fc2, WtF2, 512, 1024);

    // 2) LN both input streams -> bf16 (one launch, grid.y = stream)
    ln_dual<<<dim3(MROWS, 2), blk, 0, stream>>>(joint_feature, g1, be1, xj,
                                                relation_feature, g2, be2, xi);

    // 3+4) chunked: qkv GEMM (both streams via grid.z) then attention
    for (int c = 0; c < CH; c++) {
        size_t ro = (size_t)c * Mc * 1024;   // row offset in elements
        gemm_bt<0, 1024><<<dim3(24, Mc / 128, 2), blk, 0, stream>>>(
            xj + ro, WtJ, xi + ro, WtI, nullptr, nullptr, nullptr, Jqkv_c, Iqkv_c, 3072);
        attn_kernel<<<(Mc / 15) * 16, blk, 0, stream>>>(Jqkv_c, Iqkv_c, W_Iconv, xattn + ro);
    }

    // 5) proj + bias + residual(joint_feature) -> joint (fp32, xj+xi region)
    gemm_bt<1, 1024><<<dim3(8, 240), blk, 0, stream>>>(
        xattn, WtP, nullptr, nullptr, b_proj, joint_feature, joint, nullptr, nullptr, 1024);

    // 6) LN(joint) -> yln (xattn region)
    ln_dual<<<dim3(MROWS, 1), blk, 0, stream>>>(joint, gj, bj, yln,
                                                nullptr, nullptr, nullptr, nullptr);

    // 7) fc1 + bias + gelu -> h1 (bf16)
    gemm_bt<2, 1024><<<dim3(4, 240), blk, 0, stream>>>(
        yln, WtF1, nullptr, nullptr, b_fc1, nullptr, nullptr, h1, nullptr, 512);

    // 8) fc2 + bias + residual(joint) -> d_out (fp32)
    gemm_bt<1, 512><<<dim3(8, 240), blk, 0, stream>>>(
        h1, WtF2, nullptr, nullptr, b_fc2, joint, (float*)d_out, nullptr, nullptr, 1024);
}

// Round 3
// 1455.248 us; speedup vs baseline: 1.7897x; 1.7897x over previous
//
#include <hip/hip_runtime.h>
#include <math.h>

// ---------------------------------------------------------------------------
// B=2048, N=15, C=1024, H=16, HS=64; M = B*N = 30720 rows.
// All GEMMs: A[M][K] bf16 x Bt[N][K] bf16 (weights pre-transposed) -> C.
// m97-structure GEMM: 128x128 block tile, BK=32, global_load_lds width=16,
// ds_read_b128 fragments, 16x16x32 MFMA, 4 waves x (64x64).
// MFMA verified layouts:
//   A frag : lane holds A[m=lane&15][k=(lane>>4)*8+j], j=0..7
//   B frag : lane holds B[k=(lane>>4)*8+j][n=lane&15]  (== Bt[n][k] rows)
//   D      : lane reg r holds D[row=(lane>>4)*4+r][col=lane&15]
//
// ws-ADAPTIVE: qkv processed in CH chunks of 30720/CH rows
// (CH in {1,2,4,8,16}; chunk multiple of 1920 = lcm(128,15)).
// peak ws = 205,520,896 + 754,974,720/CH bytes  (CH=16 -> 241 MiB).
// ---------------------------------------------------------------------------

typedef __attribute__((ext_vector_type(8))) short short8;
typedef __attribute__((ext_vector_type(4))) float fx4;

#define MROWS 30720

// global(AS1) -> LDS(AS3) 16-byte async copy; LDS dest = wave-uniform base + lane*16
#define GLL16(g, l)                                                         \
    __builtin_amdgcn_global_load_lds(                                       \
        (const __attribute__((address_space(1))) unsigned int*)(g),         \
        (__attribute__((address_space(3))) unsigned int*)(l), 16, 0, 0)

__device__ inline unsigned short f2bf(float f) {
    unsigned int u = __float_as_uint(f);
    unsigned int r = (u + 0x7fffu + ((u >> 16) & 1u)) >> 16;
    return (unsigned short)r;
}
__device__ inline float bf2f(unsigned short s) {
    return __uint_as_float(((unsigned int)s) << 16);
}

// ---------------- weight transpose + bf16 cast:  W[K][N] -> Wt[N][K] --------
__global__ __launch_bounds__(256) void transpose_w(const float* __restrict__ W,
                                                   unsigned short* __restrict__ Wt,
                                                   int K, int N) {
    __shared__ float tile[32][33];
    int bn = blockIdx.x * 32;
    int bk = blockIdx.y * 32;
    int tx = threadIdx.x & 31, ty = threadIdx.x >> 5;   // 32 x 8
    #pragma unroll
    for (int i = ty; i < 32; i += 8)
        tile[i][tx] = W[(size_t)(bk + i) * N + bn + tx];
    __syncthreads();
    #pragma unroll
    for (int i = ty; i < 32; i += 8)
        Wt[(size_t)(bn + i) * K + bk + tx] = f2bf(tile[tx][i]);
}

// ---------------- LayerNorm over C=1024, fp32 in -> bf16 out ---------------
__global__ __launch_bounds__(256) void ln_dual(const float* __restrict__ xa,
                                               const float* __restrict__ ga,
                                               const float* __restrict__ bba,
                                               unsigned short* __restrict__ oa,
                                               const float* __restrict__ xb,
                                               const float* __restrict__ gb,
                                               const float* __restrict__ bbb,
                                               unsigned short* __restrict__ ob) {
    const float* x = blockIdx.y ? xb : xa;
    const float* g = blockIdx.y ? gb : ga;
    const float* bv = blockIdx.y ? bbb : bba;
    unsigned short* out = blockIdx.y ? ob : oa;

    int row = blockIdx.x;
    int t = threadIdx.x;
    const float4* xp = (const float4*)(x + (size_t)row * 1024);
    float4 v = xp[t];
    float s  = v.x + v.y + v.z + v.w;
    float ss = v.x * v.x + v.y * v.y + v.z * v.z + v.w * v.w;
    #pragma unroll
    for (int o = 32; o > 0; o >>= 1) { s += __shfl_down(s, o); ss += __shfl_down(ss, o); }
    __shared__ float ps[4], pss[4], stat[2];
    int wv = t >> 6, ln = t & 63;
    if (ln == 0) { ps[wv] = s; pss[wv] = ss; }
    __syncthreads();
    if (t == 0) {
        float S = ps[0] + ps[1] + ps[2] + ps[3];
        float SS = pss[0] + pss[1] + pss[2] + pss[3];
        float m = S * (1.0f / 1024.0f);
        float var = SS * (1.0f / 1024.0f) - m * m;
        stat[0] = m; stat[1] = rsqrtf(var + 1e-5f);
    }
    __syncthreads();
    float m = stat[0], r = stat[1];
    float4 gg = ((const float4*)g)[t];
    float4 bb = ((const float4*)bv)[t];
    ushort4 o;
    o.x = f2bf((v.x - m) * r * gg.x + bb.x);
    o.y = f2bf((v.y - m) * r * gg.y + bb.y);
    o.z = f2bf((v.z - m) * r * gg.z + bb.z);
    o.w = f2bf((v.w - m) * r * gg.w + bb.w);
    ((ushort4*)(out + (size_t)row * 1024))[t] = o;
}

// ---------------- m97-structure bf16 MFMA GEMM, fused epilogues ------------
// EPI 0: outB = bf16(acc); gridDim.z==2 selects (A,Bt,outB) vs (A2,Bt2,outB2)
// EPI 1: outF = acc + bias[col] + resid[row][col]        (fp32 out)
// EPI 2: outB = bf16(gelu_exact(acc + bias[col]))
template <int EPI, int K>
__global__ __launch_bounds__(256) void gemm_lds(const unsigned short* __restrict__ A,
                                                const unsigned short* __restrict__ Bt,
                                                const unsigned short* __restrict__ A2,
                                                const unsigned short* __restrict__ Bt2,
                                                const float* __restrict__ bias,
                                                const float* __restrict__ resid,
                                                float* __restrict__ outF,
                                                unsigned short* __restrict__ outB,
                                                unsigned short* __restrict__ outB2,
                                                int N) {
    if (EPI == 0 && blockIdx.z) { A = A2; Bt = Bt2; outB = outB2; }

    __shared__ unsigned short lA[128 * 32];   // [row][k], 32 k per row (64 B)
    __shared__ unsigned short lB[128 * 32];   // [ncol][k]

    const int t = threadIdx.x;
    const int wave = t >> 6, lane = t & 63;
    const int rowf = lane & 15, quad = lane >> 4;

    const int m0 = blockIdx.y * 128;
    const int n0 = blockIdx.x * 128;
    const int wm0 = (wave >> 1) * 64;         // wave sub-tile inside block
    const int wn0 = (wave & 1) * 64;

    // staging: chunk c = t + iter*256; row = c>>2, kchunk = (c&3)*8 elements
    const int srow = t >> 2;                  // 0..63
    const int skc  = (t & 3) * 8;             // 0/8/16/24
    const unsigned short* gA0 = A  + (size_t)(m0 + srow) * K + skc;
    const unsigned short* gA1 = A  + (size_t)(m0 + srow + 64) * K + skc;
    const unsigned short* gB0 = Bt + (size_t)(n0 + srow) * K + skc;
    const unsigned short* gB1 = Bt + (size_t)(n0 + srow + 64) * K + skc;
    unsigned short* dA0 = lA + (size_t)t * 8;          // chunk*16 bytes
    unsigned short* dA1 = lA + (size_t)(t + 256) * 8;
    unsigned short* dB0 = lB + (size_t)t * 8;
    unsigned short* dB1 = lB + (size_t)(t + 256) * 8;

    fx4 acc[4][4] = {};

    for (int k0 = 0; k0 < K; k0 += 32) {
        GLL16(gA0, dA0); GLL16(gA1, dA1);
        GLL16(gB0, dB0); GLL16(gB1, dB1);
        gA0 += 32; gA1 += 32; gB0 += 32; gB1 += 32;
        __syncthreads();                       // drains vmcnt (m97 structure)

        short8 a[4], b[4];
        #pragma unroll
        for (int i = 0; i < 4; i++)
            a[i] = *(const short8*)(lA + (wm0 + 16 * i + rowf) * 32 + quad * 8);
        #pragma unroll
        for (int j = 0; j < 4; j++)
            b[j] = *(const short8*)(lB + (wn0 + 16 * j + rowf) * 32 + quad * 8);
        #pragma unroll
        for (int i = 0; i < 4; i++)
            #pragma unroll
            for (int j = 0; j < 4; j++)
                acc[i][j] = __builtin_amdgcn_mfma_f32_16x16x32_bf16(a[i], b[j], acc[i][j], 0, 0, 0);
        __syncthreads();
    }

    #pragma unroll
    for (int i = 0; i < 4; i++) {
        #pragma unroll
        for (int j = 0; j < 4; j++) {
            int col = n0 + wn0 + 16 * j + rowf;
            #pragma unroll
            for (int r = 0; r < 4; r++) {
                int row = m0 + wm0 + 16 * i + quad * 4 + r;
                size_t off = (size_t)row * N + col;
                float v = acc[i][j][r];
                if (EPI == 0) {
                    outB[off] = f2bf(v);
                } else if (EPI == 1) {
                    outF[off] = v + bias[col] + resid[off];
                } else {
                    v += bias[col];
                    v = 0.5f * v * (1.0f + erff(v * 0.70710678118654752f));
                    outB[off] = f2bf(v);
                }
            }
        }
    }
}

// ---------------- attention: one block per (chunk-local b, h) --------------
__global__ __launch_bounds__(256) void attn_kernel(const unsigned short* __restrict__ Jqkv,
                                                   const unsigned short* __restrict__ Iqkv,
                                                   const float* __restrict__ Wc,
                                                   unsigned short* __restrict__ xout) {
    int b = blockIdx.x >> 4;
    int h = blockIdx.x & 15;
    __shared__ float J[3][15][65];
    __shared__ float I[3][15][65];
    __shared__ float W[64][17];
    __shared__ float P[15][16];

    const unsigned short* Jb = Jqkv + (size_t)b * 15 * 3072 + h * 64;
    const unsigned short* Ib = Iqkv + (size_t)b * 15 * 3072 + h * 64;

    for (int idx = threadIdx.x; idx < 15 * 3 * 64; idx += 256) {
        int n = idx / 192, rem = idx % 192;
        int r = rem / 64, d = rem % 64;
        J[r][n][d] = bf2f(Jb[(size_t)n * 3072 + r * 1024 + d]);
        I[r][n][d] = bf2f(Ib[(size_t)n * 3072 + r * 1024 + d]);
    }
    for (int idx = threadIdx.x; idx < 64 * 15; idx += 256)
        W[idx / 15][idx % 15] = Wc[idx];
    __syncthreads();

    for (int idx = threadIdx.x; idx < 225; idx += 256) {
        int q = idx / 15, kk = idx % 15;
        float s = 0.0f;
        #pragma unroll 8
        for (int d = 0; d < 64; d++)
            s += J[0][q][d] * J[1][kk][d] + I[0][q][d] * I[1][kk][d] + I[2][q][d] * W[d][kk];
        P[q][kk] = s * 0.125f;
    }
    __syncthreads();

    if (threadIdx.x < 15) {
        int q = threadIdx.x;
        float mx = -1e30f;
        #pragma unroll
        for (int kk = 0; kk < 15; kk++) mx = fmaxf(mx, P[q][kk]);
        float e[15], sum = 0.0f;
        #pragma unroll
        for (int kk = 0; kk < 15; kk++) { e[kk] = __expf(P[q][kk] - mx); sum += e[kk]; }
        float inv = 1.0f / sum;
        #pragma unroll
        for (int kk = 0; kk < 15; kk++) P[q][kk] = e[kk] * inv;
    }
    __syncthreads();

    for (int idx = threadIdx.x; idx < 960; idx += 256) {
        int q = idx >> 6, d = idx & 63;
        float o = 0.0f;
        #pragma unroll
        for (int kk = 0; kk < 15; kk++) o += P[q][kk] * J[2][kk][d];
        xout[((size_t)b * 15 + q) * 1024 + h * 64 + d] = f2bf(o);
    }
}

// ---------------------------------------------------------------------------
extern "C" void kernel_launch(void* const* d_in, const int* in_sizes, int n_in,
                              void* d_out, int out_size, void* d_ws, size_t ws_size,
                              hipStream_t stream) {
    const float* joint_feature    = (const float*)d_in[0];
    const float* relation_feature = (const float*)d_in[1];
    const float* W_Jqkv  = (const float*)d_in[2];
    const float* W_Iqk   = (const float*)d_in[3];
    const float* W_Iconv = (const float*)d_in[4];
    const float* W_proj  = (const float*)d_in[5];
    const float* b_proj  = (const float*)d_in[6];
    const float* g1  = (const float*)d_in[7];
    const float* be1 = (const float*)d_in[8];
    const float* g2  = (const float*)d_in[9];
    const float* be2 = (const float*)d_in[10];
    const float* gj  = (const float*)d_in[11];
    const float* bj  = (const float*)d_in[12];
    const float* W_fc1 = (const float*)d_in[13];
    const float* b_fc1 = (const float*)d_in[14];
    const float* W_fc2 = (const float*)d_in[15];
    const float* b_fc2 = (const float*)d_in[16];

    char* ws = (char*)d_ws;
    // -------- fixed region [0, 205,520,896) --------
    unsigned short* WtJ  = (unsigned short*)(ws + 0);          //  [3072][1024]
    unsigned short* WtI  = (unsigned short*)(ws + 6291456);    //  [3072][1024]
    unsigned short* WtP  = (unsigned short*)(ws + 12582912);   //  [1024][1024]
    unsigned short* WtF1 = (unsigned short*)(ws + 14680064);   //  [512][1024]
    unsigned short* WtF2 = (unsigned short*)(ws + 15728640);   //  [1024][512]
    unsigned short* xj   = (unsigned short*)(ws + 16777216);   //  [M][1024] bf16
    unsigned short* xi   = (unsigned short*)(ws + 79691776);   //  [M][1024] bf16
    unsigned short* xattn = (unsigned short*)(ws + 142606336); //  [M][1024] bf16
    // -------- reused regions --------
    float*          joint = (float*)(ws + 16777216);           // fp32 [M][1024] over dead xj+xi
    unsigned short* yln   = xattn;                             // xattn dead after proj
    unsigned short* h1    = (unsigned short*)(ws + 205520896); // bf16 [M][512]
    // -------- chunked qkv region --------
    int CH = 16;
    {
        const int opts[5] = {1, 2, 4, 8, 16};
        for (int i = 0; i < 5; i++) {
            size_t need = 205520896ull + 754974720ull / (size_t)opts[i];
            if (need <= ws_size) { CH = opts[i]; break; }
        }
    }
    const int Mc = MROWS / CH;                      // multiple of 1920
    const size_t chunkBytes = 754974720ull / (size_t)CH / 2ull;
    unsigned short* Jqkv_c = (unsigned short*)(ws + 205520896);
    unsigned short* Iqkv_c = (unsigned short*)(ws + 205520896 + chunkBytes);

    dim3 blk(256);

    // 1) transpose + bf16-cast weights
    transpose_w<<<dim3(96, 32), blk, 0, stream>>>(W_Jqkv, WtJ, 1024, 3072);
    transpose_w<<<dim3(96, 32), blk, 0, stream>>>(W_Iqk,  WtI, 1024, 3072);
    transpose_w<<<dim3(32, 32), blk, 0, stream>>>(W_proj, WtP, 1024, 1024);
    transpose_w<<<dim3(16, 32), blk, 0, stream>>>(W_fc1, WtF1, 1024, 512);
    transpose_w<<<dim3(32, 16), blk, 0, stream>>>(W_fc2, WtF2, 512, 1024);

    // 2) LN both input streams -> bf16
    ln_dual<<<dim3(MROWS, 2), blk, 0, stream>>>(joint_feature, g1, be1, xj,
                                                relation_feature, g2, be2, xi);

    // 3+4) chunked: qkv GEMM (both streams via grid.z) then attention
    for (int c = 0; c < CH; c++) {
        size_t ro = (size_t)c * Mc * 1024;
        gemm_lds<0, 1024><<<dim3(24, Mc / 128, 2), blk, 0, stream>>>(
            xj + ro, WtJ, xi + ro, WtI, nullptr, nullptr, nullptr, Jqkv_c, Iqkv_c, 3072);
        attn_kernel<<<(Mc / 15) * 16, blk, 0, stream>>>(Jqkv_c, Iqkv_c, W_Iconv, xattn + ro);
    }

    // 5) proj + bias + residual(joint_feature) -> joint (fp32)
    gemm_lds<1, 1024><<<dim3(8, 240), blk, 0, stream>>>(
        xattn, WtP, nullptr, nullptr, b_proj, joint_feature, joint, nullptr, nullptr, 1024);

    // 6) LN(joint) -> yln
    ln_dual<<<dim3(MROWS, 1), blk, 0, stream>>>(joint, gj, bj, yln,
                                                nullptr, nullptr, nullptr, nullptr);

    // 7) fc1 + bias + gelu -> h1 (bf16)
    gemm_lds<2, 1024><<<dim3(4, 240), blk, 0, stream>>>(
        yln, WtF1, nullptr, nullptr, b_fc1, nullptr, nullptr, h1, nullptr, 512);

    // 8) fc2 + bias + residual(joint) -> d_out (fp32)
    gemm_lds<1, 512><<<dim3(8, 240), blk, 0, stream>>>(
        h1, WtF2, nullptr, nullptr, b_fc2, joint, (float*)d_out, nullptr, nullptr, 1024);
}